// Round 10
// baseline (291.588 us; speedup 1.0000x reference)
//
#include <hip/hip_runtime.h>
#include <hip/hip_bf16.h>

// Decoder layer: self-attn (causal, shared qkv proj) + LN, cross-attn + LN,
// FFN (relu) + LN.  B=1, S=2048, D=1024, H=16, DH=64, HID=4096.
// I/O fp32.  GEMMs + attention bf16 MFMA (16x16x32), fp32 accumulate.
// Fixed-max softmax => split-K attention emits unnormalized O + l partials;
// the next LN merges.
// R20: VALU diet pass 2.  R19 accounting: pairing was ~null because
// per-SIMD work was unchanged => attn is throughput-bound on issued work
// (R18's -17% from VALU cuts is the only lever that pays 1:1).  Cuts:
// (1) template<bool CAUSAL> -- cross no longer executes act/diag/mask code
//     at runtime (was evaluated every iteration for nothing);
// (2) exp via single mul (s*0.125*log2e) + inline-asm v_exp_f32 (2^x),
//     replacing __expf's mul+mul+exp;
// (3) pointer-increment staging (attn + GEMM): ptr += const replaces
//     per-iter base + kt*stride 64-bit recompute;
// (4) v_cvt_pk_bf16_f32 packing in GEMM DUALT epilogue / LN DUAL / conv.
// Structure (buffers, barriers, grids, tiles) = R19 exactly.
// 128B LDS rows use chunk ^= row&7 swizzle; 64B rows (V,P) use
// chunk ^= (row>>1)&3 -- applied on the GLOBAL fetch address so
// global_load_lds's lane-linear dest lands data where conflict-minimal
// ds_read_b128 fragment reads expect it.

#define S_LEN 2048
#define DMODEL 1024
#define NHEAD 16
#define DHEAD 64
#define HIDDEN 4096

using bf16 = __hip_bfloat16;
typedef __attribute__((ext_vector_type(8))) short bf16x8;
typedef __attribute__((ext_vector_type(4))) float floatx4;

__device__ __forceinline__ void async_ld16(const void* g, void* l) {
  __builtin_amdgcn_global_load_lds(
      (const __attribute__((address_space(1))) unsigned int*)g,
      (__attribute__((address_space(3))) unsigned int*)l, 16, 0, 0);
}

__device__ __forceinline__ unsigned short f2bf_bits(float f) {
  __hip_bfloat16 b = __float2bfloat16(f);
  return *(unsigned short*)&b;
}

__device__ __forceinline__ unsigned int pk_bf16(float a, float b) {
  unsigned int r;
  asm("v_cvt_pk_bf16_f32 %0, %1, %2" : "=v"(r) : "v"(a), "v"(b));
  return r;
}

// ---------------------------------------------------------------------------
// Transpose-convert weights: src fp32 (K x N, or head-blocked (H,K,64)) ->
// dst bf16 [N][K].  32x32 LDS tile, block 256 (32x8).  grid.z selects pair.
// ---------------------------------------------------------------------------
template <bool HEADB>
__global__ __launch_bounds__(256) void transp_bf16_kernel(
    const float* __restrict__ src0, bf16* __restrict__ dst0,
    const float* __restrict__ src1, bf16* __restrict__ dst1, int K, int N) {
  const float* src = blockIdx.z ? src1 : src0;
  bf16* dst = blockIdx.z ? dst1 : dst0;
  __shared__ float tile[32][33];
  const int tx = threadIdx.x & 31, ty = threadIdx.x >> 5;
  const int k0 = blockIdx.y * 32, n0 = blockIdx.x * 32;
#pragma unroll
  for (int i = 0; i < 4; ++i) {
    const int k = k0 + ty + i * 8;
    const int n = n0 + tx;
    size_t idx;
    if (HEADB)
      idx = (size_t)(n >> 6) * ((size_t)K * 64) + (size_t)k * 64 + (n & 63);
    else
      idx = (size_t)k * N + n;
    tile[ty + i * 8][tx] = src[idx];
  }
  __syncthreads();
#pragma unroll
  for (int i = 0; i < 4; ++i) {
    const int n = n0 + ty + i * 8;
    const int k = k0 + tx;
    dst[(size_t)n * K + k] = __float2bfloat16(tile[tx][ty + i * 8]);
  }
}

// straight fp32 -> bf16, 4 elements/thread; grid.z selects src/dst pair
__global__ __launch_bounds__(256) void conv_bf16_kernel(
    const float* __restrict__ src0, bf16* __restrict__ dst0,
    const float* __restrict__ src1, bf16* __restrict__ dst1, int n4) {
  const float* src = blockIdx.z ? src1 : src0;
  bf16* dst = blockIdx.z ? dst1 : dst0;
  const int i = blockIdx.x * 256 + threadIdx.x;
  if (i >= n4) return;
  float4 v = ((const float4*)src)[i];
  ((uint2*)dst)[i] = make_uint2(pk_bf16(v.x, v.y), pk_bf16(v.z, v.w));
}

// ---------------------------------------------------------------------------
// MFMA GEMM: C[M,N] = A[M,Klen] @ Bt[N,Klen]^T (+ bias[N]), optional ReLU.
// Rows strided by Kstride (split-K via pre-offset ptrs).  BK=64: LDS rows are
// 128B / 8 chunks, XOR-swizzled.  Double-buffered 2-phase pipeline: ds_reads
// of tile t first, then stage(t+1) (global_load_lds, no wait), then MFMA;
// one __syncthreads per tile.  Staging sources advance by pointer increment.
// BM in {32,64,128}, BN in {64,128}; 256 thr = 4 waves in 2x2.
// DUALT: also emit C^T bf16 (cvt_pk packed).  grid.z selects problem 0/1.
// ---------------------------------------------------------------------------
template <int BM, int BN, bool RELU, bool DUALT, typename CT>
__global__ __launch_bounds__(256) void mfma_gemm_kernel(
    const bf16* __restrict__ A0, const bf16* __restrict__ Bt0,
    const float* __restrict__ bias0, CT* __restrict__ C0,
    bf16* __restrict__ Ct0,
    const bf16* __restrict__ A1, const bf16* __restrict__ Bt1,
    const float* __restrict__ bias1, CT* __restrict__ C1,
    bf16* __restrict__ Ct1,
    int M, int N, int Kstride, int Klen) {
  const bf16* A = blockIdx.z ? A1 : A0;
  const bf16* Bt = blockIdx.z ? Bt1 : Bt0;
  const float* bias = blockIdx.z ? bias1 : bias0;
  CT* C = blockIdx.z ? C1 : C0;
  bf16* Ct = blockIdx.z ? Ct1 : Ct0;

  constexpr int MF = (BM + 31) / 32;
  constexpr int NF = BN / 32;
  __shared__ __align__(16) bf16 As[2][BM * 64];
  __shared__ __align__(16) bf16 Bs[2][BN * 64];

  const int tid = threadIdx.x;
  const int wave = tid >> 6;
  const int lane = tid & 63;
  const int m0 = blockIdx.y * BM;
  const int n0 = blockIdx.x * BN;
  const int wr = wave >> 1, wc = wave & 1;

  // staging: thread -> row tid>>3 (32 rows / 4096B issue), swizzled chunk
  const int srow = tid >> 3;
  const int schunk = (tid & 7) ^ (srow & 7);
  const bf16* astg = A + (size_t)(m0 + srow) * Kstride + schunk * 8;
  const bf16* bstg = Bt + (size_t)(n0 + srow) * Kstride + schunk * 8;

  floatx4 acc[MF][NF];
#pragma unroll
  for (int i = 0; i < MF; ++i)
#pragma unroll
    for (int j = 0; j < NF; ++j) acc[i][j] = floatx4{0.f, 0.f, 0.f, 0.f};

  const int mrow = lane & 15;
  const int p0 = (((lane >> 4) ^ (mrow & 7)) << 4);  // swizzled chunk pos
  const int p1 = p0 ^ 64;                            // k-step 1 (chunk+4)

  auto stage = [&](int buf) {
    char* al = (char*)As + buf * (BM * 128) + wave * 1024;
    char* bl = (char*)Bs + buf * (BN * 128) + wave * 1024;
#pragma unroll
    for (int i = 0; i < BM / 32; ++i)
      async_ld16(astg + (size_t)(32 * i) * Kstride, al + i * 4096);
#pragma unroll
    for (int i = 0; i < BN / 32; ++i)
      async_ld16(bstg + (size_t)(32 * i) * Kstride, bl + i * 4096);
  };

  stage(0);
  astg += 64;
  bstg += 64;
  __syncthreads();  // drains vmcnt(0): buffer 0 ready

  int cur = 0;
  for (int kt = 0; kt < Klen; kt += 64) {
    const char* abase = (const char*)As + cur * (BM * 128);
    const char* bbase = (const char*)Bs + cur * (BN * 128);
    bf16x8 af0[MF], af1[MF], bf0[NF], bf1[NF];
#pragma unroll
    for (int fi = 0; fi < MF; ++fi) {
      const char* ar = abase + (wr * (BM / 2) + fi * 16 + mrow) * 128;
      af0[fi] = *(const bf16x8*)(ar + p0);
      af1[fi] = *(const bf16x8*)(ar + p1);
    }
#pragma unroll
    for (int fj = 0; fj < NF; ++fj) {
      const char* br = bbase + (wc * (BN / 2) + fj * 16 + mrow) * 128;
      bf0[fj] = *(const bf16x8*)(br + p0);
      bf1[fj] = *(const bf16x8*)(br + p1);
    }

    if (kt + 64 < Klen) {  // prefetch, no wait
      stage(cur ^ 1);
      astg += 64;
      bstg += 64;
    }

#pragma unroll
    for (int fi = 0; fi < MF; ++fi)
#pragma unroll
      for (int fj = 0; fj < NF; ++fj) {
        acc[fi][fj] = __builtin_amdgcn_mfma_f32_16x16x32_bf16(
            af0[fi], bf0[fj], acc[fi][fj], 0, 0, 0);
        acc[fi][fj] = __builtin_amdgcn_mfma_f32_16x16x32_bf16(
            af1[fi], bf1[fj], acc[fi][fj], 0, 0, 0);
      }

    __syncthreads();  // next-tile loads landed; all reads of cur done
    cur ^= 1;
  }

  const int erow = (lane >> 4) * 4;
  const int ecol = lane & 15;
#pragma unroll
  for (int fi = 0; fi < MF; ++fi) {
#pragma unroll
    for (int fj = 0; fj < NF; ++fj) {
      const int nn = n0 + wc * (BN / 2) + fj * 16 + ecol;
      const float bv = bias ? bias[nn] : 0.0f;
      const int mmb = m0 + wr * (BM / 2) + fi * 16 + erow;
      float v[4];
#pragma unroll
      for (int r = 0; r < 4; ++r) {
        v[r] = acc[fi][fj][r] + bv;
        if (RELU) v[r] = fmaxf(v[r], 0.0f);
        if constexpr (sizeof(CT) == 2)
          C[(size_t)(mmb + r) * N + nn] = (CT)__float2bfloat16(v[r]);
        else
          C[(size_t)(mmb + r) * N + nn] = (CT)v[r];
      }
      if (DUALT) {
        *(uint2*)&Ct[(size_t)nn * M + mmb] =
            make_uint2(pk_bf16(v[0], v[1]), pk_bf16(v[2], v[3]));
      }
    }
  }
}

// ---------------------------------------------------------------------------
// MFMA flash attention, fixed-max softmax, split-K partials (k == v).
// Block = 256 thr = 4 waves; wave owns 16 q of a 64-q tile.  KV tile = 32 t.
// K/V double-buffered; loop unrolled by 2 (buf0/buf1 phases): every swizzled
// LDS offset is loop-invariant, staging sources advance by pointer increment.
// exp via single mul (0.125*log2e) + v_exp_f32.  P pack via cvt_pk.
// LDS = 20KB.  CAUSAL (template): pair-scheduling -- block processes q-tiles
// {qb0, 31-qb0} sequentially (uniform 33 iters), grid (16,16,2); masks/pass
// loop compiled out of the cross instantiation (grid (32,16,2)).
// Kt rows 128B (chunk ^= row&7); Vs/Ps rows 64B (chunk ^= (row>>1)&3), both
// pre-applied on the global fetch address (lane-linear LDS dest).
// S^T = K.Q^T (C: 4 consecutive t per lane at fixed q) -> P stores are 8B,
// l-reduce is 2 shuffles.  PV: O^T = V^T @ P^T, k=32 in one MFMA per d-block.
// Emits UNNORMALIZED O-partial + l-partial; LN merges.
// ---------------------------------------------------------------------------
template <bool CAUSAL>
__global__ __launch_bounds__(256) void mfma_attn_kernel(
    const bf16* __restrict__ Q, const bf16* __restrict__ K,
    const bf16* __restrict__ Vt,
    float* __restrict__ OA, float* __restrict__ OB,
    float* __restrict__ LA, float* __restrict__ LB) {
  __shared__ __align__(16) unsigned short Kt[2][32 * 64];  // [t][d] swizzled
  __shared__ __align__(16) unsigned short Vs[2][64 * 32];  // [d][t] swizzled
  __shared__ __align__(16) unsigned short Ps[4][512];      // per-wave P [q][t]

  const int tid = threadIdx.x;
  const int w = tid >> 6, lane = tid & 63;
  const int g = lane >> 4, c = lane & 15;
  const int h = blockIdx.y;
  const int z = blockIdx.z;
  float* Oz = z ? OB : OA;
  float* Lz = z ? LB : LA;

  // staging addresses (global pre-swizzled, LDS dest lane-linear)
  const int srk = tid >> 3;                        // K row 0..31 (128B rows)
  const int sck = (tid & 7) ^ (srk & 7);
  const bf16* kgp = K + (size_t)srk * DMODEL + h * DHEAD + sck * 8;
  const int srv = tid >> 2;                        // V row 0..63 (64B rows)
  const int scv = (tid & 3) ^ ((srv >> 1) & 3);
  const bf16* vgp = Vt + (size_t)(h * DHEAD + srv) * S_LEN + scv * 8;

  const int kpos0 = ((g ^ (c & 7)) << 4);
  const int kpos1 = kpos0 ^ 64;
  const int vpos = ((g ^ ((c >> 1) & 3)) << 4);    // also the P-read pos
  char* pswave = (char*)Ps + w * 1024;

  // ---- lane-invariant LDS byte offsets (hoisted; pass-invariant too) ----
  const int ko00 = c * 128 + kpos0, ko01 = c * 128 + kpos1;
  const int ko10 = (16 + c) * 128 + kpos0, ko11 = (16 + c) * 128 + kpos1;
  const int vo0 = c * 64 + vpos, vo1 = (16 + c) * 64 + vpos;
  const int vo2 = (32 + c) * 64 + vpos, vo3 = (48 + c) * 64 + vpos;
  char* const pw0 = pswave + c * 64 +
      ((((g >> 1) ^ ((c >> 1) & 3)) << 4) | ((g & 1) << 3));        // jt=0
  char* const pw1 = pswave + c * 64 +
      ((((2 + (g >> 1)) ^ ((c >> 1) & 3)) << 4) | ((g & 1) << 3));  // jt=1
  const char* const pr = pswave + vo0;

  const int npass = CAUSAL ? 2 : 1;
  for (int pass = 0; pass < npass; ++pass) {
    // causal pairing: pass 0 -> qb0 (short), pass 1 -> 31-qb0 (long)
    const int qb = CAUSAL ? (pass ? (S_LEN / 64 - 1) - (int)blockIdx.x
                                  : (int)blockIdx.x)
                          : (int)blockIdx.x;
    const int q0 = qb * 64;
    const int qw = q0 + w * 16;  // this wave's 16-q subtile

    // Q B-frags for the wave's 16-q subtile (d halves 0..31 / 32..63)
    const bf16* qrow = Q + (size_t)(qw + c) * DMODEL + h * DHEAD + g * 8;
    const bf16x8 qfa = *(const bf16x8*)qrow;
    const bf16x8 qfb = *(const bf16x8*)(qrow + 32);

    floatx4 of0{0.f, 0.f, 0.f, 0.f}, of1{0.f, 0.f, 0.f, 0.f};
    floatx4 of2{0.f, 0.f, 0.f, 0.f}, of3{0.f, 0.f, 0.f, 0.f};
    float lp0 = 0.f, lp1 = 0.f;

    const int nkt = CAUSAL ? (q0 / 32 + 2) : (S_LEN / 32);

    // running stage source pointers (advance by increment, no per-iter mul)
    const bf16* kst = kgp + (size_t)(z * 32) * DMODEL;
    const bf16* vst = vgp + z * 32;

    auto phase = [&](const char* kb, const char* vb, int sbuf, int kt) {
      bool act = true;
      if constexpr (CAUSAL) act = !(kt * 32 >= qw + 16);  // wave-uniform
      bf16x8 kf00, kf01, kf10, kf11, vf0, vf1, vf2, vf3;
      if (act) {
        kf00 = *(const bf16x8*)(kb + ko00);
        kf01 = *(const bf16x8*)(kb + ko01);
        kf10 = *(const bf16x8*)(kb + ko10);
        kf11 = *(const bf16x8*)(kb + ko11);
        vf0 = *(const bf16x8*)(vb + vo0);
        vf1 = *(const bf16x8*)(vb + vo1);
        vf2 = *(const bf16x8*)(vb + vo2);
        vf3 = *(const bf16x8*)(vb + vo3);
      }
      if (kt + 2 < nkt) {  // prefetch next, no wait
        async_ld16(kst, (char*)Kt + sbuf * 4096 + w * 1024);
        async_ld16(vst, (char*)Vs + sbuf * 4096 + w * 1024);
        kst += (size_t)64 * DMODEL;
        vst += 64;
      }
      if (act) {
#pragma unroll
        for (int jt = 0; jt < 2; ++jt) {
          floatx4 s = floatx4{0.f, 0.f, 0.f, 0.f};
          __builtin_amdgcn_s_setprio(1);
          s = __builtin_amdgcn_mfma_f32_16x16x32_bf16(jt ? kf10 : kf00, qfa, s, 0, 0, 0);
          s = __builtin_amdgcn_mfma_f32_16x16x32_bf16(jt ? kf11 : kf01, qfb, s, 0, 0, 0);
          __builtin_amdgcn_s_setprio(0);

          // p = exp(0.125*s) = 2^(s * 0.125*log2e)
          const float C = 0.18033688011f;
          float e0, e1, e2, e3;
          {
            float x0 = s[0] * C, x1 = s[1] * C, x2 = s[2] * C, x3 = s[3] * C;
            asm("v_exp_f32 %0, %1" : "=v"(e0) : "v"(x0));
            asm("v_exp_f32 %0, %1" : "=v"(e1) : "v"(x1));
            asm("v_exp_f32 %0, %1" : "=v"(e2) : "v"(x2));
            asm("v_exp_f32 %0, %1" : "=v"(e3) : "v"(x3));
          }
          if constexpr (CAUSAL) {
            const bool diag = (kt * 32 + 32 > qw);
            if (diag) {
              const int tb = kt * 32 + 16 * jt + 4 * g;
              const int qq = qw + c;
              if (tb + 0 > qq) e0 = 0.f;
              if (tb + 1 > qq) e1 = 0.f;
              if (tb + 2 > qq) e2 = 0.f;
              if (tb + 3 > qq) e3 = 0.f;
            }
          }
          lp0 += e0 + e1;
          lp1 += e2 + e3;
          *(uint2*)(jt ? pw1 : pw0) =
              make_uint2(pk_bf16(e0, e1), pk_bf16(e2, e3));
        }

        // --- O^T += V^T @ P^T (k = 32 in one MFMA per d-block) ---
        const bf16x8 pf = *(const bf16x8*)pr;
        __builtin_amdgcn_s_setprio(1);
        of0 = __builtin_amdgcn_mfma_f32_16x16x32_bf16(vf0, pf, of0, 0, 0, 0);
        of1 = __builtin_amdgcn_mfma_f32_16x16x32_bf16(vf1, pf, of1, 0, 0, 0);
        of2 = __builtin_amdgcn_mfma_f32_16x16x32_bf16(vf2, pf, of2, 0, 0, 0);
        of3 = __builtin_amdgcn_mfma_f32_16x16x32_bf16(vf3, pf, of3, 0, 0, 0);
        __builtin_amdgcn_s_setprio(0);
      }
      __syncthreads();  // next-tile loads landed; all reads of this buf done
    };

    // prologue: stage tile z into buf0
    async_ld16(kst, (char*)Kt + w * 1024);
    async_ld16(vst, (char*)Vs + w * 1024);
    kst += (size_t)64 * DMODEL;
    vst += 64;
    __syncthreads();  // buffer 0 ready (drains vmcnt)

    int kt = z;
    while (true) {
      phase((const char*)Kt, (const char*)Vs, 1, kt);  // compute buf0
      kt += 2;
      if (kt >= nkt) break;
      phase((const char*)Kt + 4096, (const char*)Vs + 4096, 0, kt);
      kt += 2;
      if (kt >= nkt) break;
    }

    // --- l reduce (over g-groups) + unnormalized O-partial write ---
    float lpart = lp0 + lp1;
    lpart += __shfl_xor(lpart, 16, 64);
    lpart += __shfl_xor(lpart, 32, 64);
    if (g == 0) Lz[(size_t)h * S_LEN + qw + c] = lpart;
    float* orow = Oz + (size_t)(qw + c) * DMODEL + h * DHEAD;
    {
      float4 v;
      v.x = of0[0]; v.y = of0[1]; v.z = of0[2]; v.w = of0[3];
      *(float4*)(orow + 0 * 16 + 4 * g) = v;
      v.x = of1[0]; v.y = of1[1]; v.z = of1[2]; v.w = of1[3];
      *(float4*)(orow + 1 * 16 + 4 * g) = v;
      v.x = of2[0]; v.y = of2[1]; v.z = of2[2]; v.w = of2[3];
      *(float4*)(orow + 2 * 16 + 4 * g) = v;
      v.x = of3[0]; v.y = of3[1]; v.z = of3[2]; v.w = of3[3];
      *(float4*)(orow + 3 * 16 + 4 * g) = v;
    }
    // next pass: prologue stage + barrier re-fills LDS; epilogue touched no
    // LDS, and the last phase's __syncthreads() ordered all reads before it.
  }
}

// ---------------------------------------------------------------------------
// LayerNorm variants.  One block (256 thr) per row, D=1024; float4 per thread.
// MERGE: x = X + (R+R2) / (La[h][row]+Lb[h][row])   (attention partial merge)
// SUM2 : x = X + R + R2 + bvec                      (split-K FFN + bias)
// else : x = X + R
// ---------------------------------------------------------------------------
template <bool DUAL, bool MERGE, bool SUM2>
__global__ __launch_bounds__(256) void add_ln_kernel(
    const float* __restrict__ X, const float* __restrict__ R,
    const float* __restrict__ R2, const float* __restrict__ bvec,
    const float* __restrict__ La, const float* __restrict__ Lb,
    const float* __restrict__ g, const float* __restrict__ beta,
    float* __restrict__ out, bf16* __restrict__ out2) {
  const int row = blockIdx.x;
  const int tid = threadIdx.x;
  const int c = tid * 4;
  const size_t base = (size_t)row * DMODEL + c;

  float4 x = *(const float4*)&X[base];
  if (MERGE) {
    const int h = c >> 6;
    const float rl =
        1.0f / (La[(size_t)h * S_LEN + row] + Lb[(size_t)h * S_LEN + row]);
    const float4 r = *(const float4*)&R[base];
    const float4 r2 = *(const float4*)&R2[base];
    x.x += (r.x + r2.x) * rl;
    x.y += (r.y + r2.y) * rl;
    x.z += (r.z + r2.z) * rl;
    x.w += (r.w + r2.w) * rl;
  } else if (SUM2) {
    const float4 r = *(const float4*)&R[base];
    const float4 r2 = *(const float4*)&R2[base];
    const float4 bv = *(const float4*)&bvec[c];
    x.x += r.x + r2.x + bv.x;
    x.y += r.y + r2.y + bv.y;
    x.z += r.z + r2.z + bv.z;
    x.w += r.w + r2.w + bv.w;
  } else {
    const float4 r = *(const float4*)&R[base];
    x.x += r.x; x.y += r.y; x.z += r.z; x.w += r.w;
  }
  float s1 = x.x + x.y + x.z + x.w;
  float s2 = x.x * x.x + x.y * x.y + x.z * x.z + x.w * x.w;

#pragma unroll
  for (int off = 32; off; off >>= 1) {
    s1 += __shfl_xor(s1, off, 64);
    s2 += __shfl_xor(s2, off, 64);
  }
  __shared__ float w1s[4], w2s[4];
  const int wid = tid >> 6, lane = tid & 63;
  if (lane == 0) { w1s[wid] = s1; w2s[wid] = s2; }
  __syncthreads();
  s1 = w1s[0] + w1s[1] + w1s[2] + w1s[3];
  s2 = w2s[0] + w2s[1] + w2s[2] + w2s[3];

  const float mu = s1 * (1.0f / DMODEL);
  const float var = s2 * (1.0f / DMODEL) - mu * mu;
  const float rstd = rsqrtf(var + 1e-5f);

  const float4 gg = *(const float4*)&g[c];
  const float4 bb = *(const float4*)&beta[c];
  float4 r;
  r.x = (x.x - mu) * rstd * gg.x + bb.x;
  r.y = (x.y - mu) * rstd * gg.y + bb.y;
  r.z = (x.z - mu) * rstd * gg.z + bb.z;
  r.w = (x.w - mu) * rstd * gg.w + bb.w;
  *(float4*)&out[base] = r;
  if (DUAL) {
    *(uint2*)&out2[base] = make_uint2(pk_bf16(r.x, r.y), pk_bf16(r.z, r.w));
  }
}

// ---------------------------------------------------------------------------
extern "C" void kernel_launch(void* const* d_in, const int* in_sizes, int n_in,
                              void* d_out, int out_size, void* d_ws, size_t ws_size,
                              hipStream_t stream) {
  const float* y      = (const float*)d_in[0];
  const float* enc    = (const float*)d_in[1];
  const float* Wself  = (const float*)d_in[2];
  const float* bself  = (const float*)d_in[3];
  const float* Wcross = (const float*)d_in[4];
  const float* bcross = (const float*)d_in[5];
  const float* g1     = (const float*)d_in[6];
  const float* be1    = (const float*)d_in[7];
  const float* g2     = (const float*)d_in[8];
  const float* be2    = (const float*)d_in[9];
  const float* g3     = (const float*)d_in[10];
  const float* be3    = (const float*)d_in[11];
  const float* w1     = (const float*)d_in[12];
  const float* b1     = (const float*)d_in[13];
  const float* w2     = (const float*)d_in[14];
  const float* b2     = (const float*)d_in[15];
  float* out = (float*)d_out;

  char* ws = (char*)d_ws;
  const size_t MB = 1024 * 1024;
  bf16*  ybf   = (bf16*)(ws + 0 * MB);
  bf16*  encbf = (bf16*)(ws + 4 * MB);
  float* PA    = (float*)(ws + 0 * MB);
  float* PB    = (float*)(ws + 8 * MB);
  float* Y1    = (float*)(ws + 16 * MB);
  float* Y2    = (float*)(ws + 24 * MB);
  bf16*  Q12b  = (bf16*)(ws + 32 * MB);
  bf16*  Q1t   = (bf16*)(ws + 36 * MB);
  bf16*  K2b   = (bf16*)(ws + 40 * MB);
  bf16*  K2t   = (bf16*)(ws + 44 * MB);
  bf16*  w1t   = (bf16*)(ws + 48 * MB);
  bf16*  w2t   = (bf16*)(ws + 56 * MB);
  bf16*  Wst   = (bf16*)(ws + 64 * MB);
  bf16*  Wct   = (bf16*)(ws + 66 * MB);
  bf16*  Y1bf  = (bf16*)(ws + 68 * MB);
  bf16*  Y2bf  = (bf16*)(ws + 72 * MB);
  float* La    = (float*)(ws + 76 * MB);
  float* Lb    = (float*)(ws + 76 * MB + 512 * 1024);
  bf16*  FFH   = (bf16*)(ws + 0 * MB);    // 16 MB, overlays dead PA+PB
  float* FFa   = (float*)(ws + 32 * MB);  // overlays dead Q12b+Q1t
  float* FFb   = (float*)(ws + 40 * MB);  // overlays dead K2b+K2t

  const dim3 blk(256);
  const dim3 gT_w(DMODEL / 32, DMODEL / 32, 2);
  const dim3 gT_w1(HIDDEN / 32, DMODEL / 32);
  const dim3 gT_w2(DMODEL / 32, HIDDEN / 32);
  const dim3 gConv(S_LEN * DMODEL / 4 / 256, 1, 2);
  const dim3 gProj2(DMODEL / 64, S_LEN / 128, 2);   // 512 blocks (128x64)
  const dim3 gProj(DMODEL / 64, S_LEN / 64);        // 512 (64x64)
  const dim3 gFf1(HIDDEN / 128, S_LEN / 128);       // 512 (128x128)
  const dim3 gFf2(DMODEL / 64, S_LEN / 128, 2);     // 512 (128x64 split-K)
  const dim3 gAttnC(S_LEN / 128, NHEAD, 2);         // 512 (paired causal)
  const dim3 gAttnX(S_LEN / 64, NHEAD, 2);          // 1024 (cross)
  const dim3 gLn(S_LEN);

  // --- conversions ---
  transp_bf16_kernel<true><<<gT_w, blk, 0, stream>>>(
      Wself, Wst, Wcross, Wct, DMODEL, DMODEL);
  transp_bf16_kernel<false><<<gT_w1, blk, 0, stream>>>(
      w1, w1t, nullptr, nullptr, DMODEL, HIDDEN);
  transp_bf16_kernel<false><<<gT_w2, blk, 0, stream>>>(
      w2, w2t, nullptr, nullptr, HIDDEN, DMODEL);
  conv_bf16_kernel<<<gConv, blk, 0, stream>>>(
      y, ybf, enc, encbf, S_LEN * DMODEL / 4);

  // 1+4) Q1 = y@Wself+bself ; K2 = enc@Wcross+bcross  (dual C+C^T, one launch)
  mfma_gemm_kernel<128, 64, false, true, bf16><<<gProj2, blk, 0, stream>>>(
      ybf, Wst, bself, Q12b, Q1t,
      encbf, Wct, bcross, K2b, K2t, S_LEN, DMODEL, DMODEL, DMODEL);
  // 2) self-attention (causal, paired q-tiles), k=v=Q1; unnormalized partials
  mfma_attn_kernel<true><<<gAttnC, blk, 0, stream>>>(
      Q12b, Q12b, Q1t, PA, PB, La, Lb);
  // 3) y1 = LN(y + (PA+PB)/(La+Lb))  (+ bf16 copy)
  add_ln_kernel<true, true, false><<<gLn, blk, 0, stream>>>(
      y, PA, PB, nullptr, La, Lb, g1, be1, Y1, Y1bf);
  // 5) Q2 = y1 @ Wcross + bcross  (64x64: 512 blocks)
  mfma_gemm_kernel<64, 64, false, false, bf16><<<gProj, blk, 0, stream>>>(
      Y1bf, Wct, bcross, Q12b, nullptr,
      nullptr, nullptr, nullptr, nullptr, nullptr, S_LEN, DMODEL, DMODEL, DMODEL);
  // 6) cross-attention (full), k=v=K2
  mfma_attn_kernel<false><<<gAttnX, blk, 0, stream>>>(
      Q12b, K2b, K2t, PA, PB, La, Lb);
  // 7) y2 = LN(y1 + (PA+PB)/(La+Lb))  (+ bf16 copy)
  add_ln_kernel<true, true, false><<<gLn, blk, 0, stream>>>(
      Y1, PA, PB, nullptr, La, Lb, g2, be2, Y2, Y2bf);
  // 8) ffh = relu(y2 @ w1 + b1) -> bf16  (128x128: 512 blocks)
  mfma_gemm_kernel<128, 128, true, false, bf16><<<gFf1, blk, 0, stream>>>(
      Y2bf, w1t, b1, FFH, nullptr,
      nullptr, nullptr, nullptr, nullptr, nullptr, S_LEN, HIDDEN, DMODEL, DMODEL);
  // 9) split-K FFN2 (128x64: 512 blocks, K=2048 each)
  mfma_gemm_kernel<128, 64, false, false, float><<<gFf2, blk, 0, stream>>>(
      FFH, w2t, nullptr, FFa, nullptr,
      FFH + HIDDEN / 2, w2t + HIDDEN / 2, nullptr, FFb, nullptr,
      S_LEN, DMODEL, HIDDEN, HIDDEN / 2);
  // 10) out = LN(y2 + FFa + FFb + b2)
  add_ln_kernel<false, false, true><<<gLn, blk, 0, stream>>>(
      Y2, FFa, FFb, b2, nullptr, nullptr, g3, be3, out, nullptr);
}

// Round 11
// 279.635 us; speedup vs baseline: 1.0427x; 1.0427x over previous
//
#include <hip/hip_runtime.h>
#include <hip/hip_bf16.h>

// Decoder layer: self-attn (causal, shared qkv proj) + LN, cross-attn + LN,
// FFN (relu) + LN.  B=1, S=2048, D=1024, H=16, DH=64, HID=4096.
// I/O fp32.  GEMMs + attention bf16 MFMA (16x16x32), fp32 accumulate.
// Fixed-max softmax => split-K attention emits unnormalized O + l partials;
// the next LN merges.
// R21: (a) attn KV tile 32 -> 64: halves barrier/loop count (R20 null =>
// per-iter VALU exhausted; remaining per-iter cost is fixed structural:
// barrier+drain+prefetch+control, paid 33x -> now 17x).  Same per-element
// work; LDS 20->40KB (still 4 blk/CU).  K rows unchanged (128B, ^row&7);
// V and P move to 128B rows / 8-chunk XOR; P write chunk (2jt+(g>>1))^(c&7)
// + (g&1)*8 matches read chunk (4ks+g)^(c&7) (same row key, bijective).
// Element masks already zero fully-masked diag fragments (no new logic).
// (b) 3 transposes + conv fused into ONE 14336-block launch (saves 3
// serial-graph dispatch gaps).  GEMMs / LNs = R20 exactly.
// 128B LDS rows use chunk ^= row&7 swizzle applied on the GLOBAL fetch
// address so global_load_lds's lane-linear dest lands data where
// conflict-minimal ds_read_b128 fragment reads expect it.

#define S_LEN 2048
#define DMODEL 1024
#define NHEAD 16
#define DHEAD 64
#define HIDDEN 4096

using bf16 = __hip_bfloat16;
typedef __attribute__((ext_vector_type(8))) short bf16x8;
typedef __attribute__((ext_vector_type(4))) float floatx4;

__device__ __forceinline__ void async_ld16(const void* g, void* l) {
  __builtin_amdgcn_global_load_lds(
      (const __attribute__((address_space(1))) unsigned int*)g,
      (__attribute__((address_space(3))) unsigned int*)l, 16, 0, 0);
}

__device__ __forceinline__ unsigned short f2bf_bits(float f) {
  __hip_bfloat16 b = __float2bfloat16(f);
  return *(unsigned short*)&b;
}

__device__ __forceinline__ unsigned int pk_bf16(float a, float b) {
  unsigned int r;
  asm("v_cvt_pk_bf16_f32 %0, %1, %2" : "=v"(r) : "v"(a), "v"(b));
  return r;
}

// ---------------------------------------------------------------------------
// Fused conversions: one launch does
//   blocks [0,2048)      : Wself/Wcross head-blocked transpose (32x32x2)
//   blocks [2048,6144)   : w1 transpose  (grid 128x32)
//   blocks [6144,10240)  : w2 transpose  (grid 32x128)
//   blocks [10240,14336) : y/enc fp32->bf16 (2048 x 2)
// ---------------------------------------------------------------------------
template <bool HEADB>
__device__ __forceinline__ void transp_body(
    const float* __restrict__ src, bf16* __restrict__ dst, int K, int N,
    int bx, int by, float (*tile)[33]) {
  const int tx = threadIdx.x & 31, ty = threadIdx.x >> 5;
  const int k0 = by * 32, n0 = bx * 32;
#pragma unroll
  for (int i = 0; i < 4; ++i) {
    const int k = k0 + ty + i * 8;
    const int n = n0 + tx;
    size_t idx;
    if (HEADB)
      idx = (size_t)(n >> 6) * ((size_t)K * 64) + (size_t)k * 64 + (n & 63);
    else
      idx = (size_t)k * N + n;
    tile[ty + i * 8][tx] = src[idx];
  }
  __syncthreads();
#pragma unroll
  for (int i = 0; i < 4; ++i) {
    const int n = n0 + ty + i * 8;
    const int k = k0 + tx;
    dst[(size_t)n * K + k] = __float2bfloat16(tile[tx][ty + i * 8]);
  }
}

__global__ __launch_bounds__(256) void fused_conv_kernel(
    const float* __restrict__ Wself, bf16* __restrict__ Wst,
    const float* __restrict__ Wcross, bf16* __restrict__ Wct,
    const float* __restrict__ w1, bf16* __restrict__ w1t,
    const float* __restrict__ w2, bf16* __restrict__ w2t,
    const float* __restrict__ y, bf16* __restrict__ ybf,
    const float* __restrict__ enc, bf16* __restrict__ encbf) {
  __shared__ float tile[32][33];
  const int id = blockIdx.x;
  if (id < 2048) {
    const int p = id >> 10, r = id & 1023;
    transp_body<true>(p ? Wcross : Wself, p ? Wct : Wst, DMODEL, DMODEL,
                      r & 31, r >> 5, tile);
  } else if (id < 6144) {
    const int r = id - 2048;
    transp_body<false>(w1, w1t, DMODEL, HIDDEN, r & 127, r >> 7, tile);
  } else if (id < 10240) {
    const int r = id - 6144;
    transp_body<false>(w2, w2t, HIDDEN, DMODEL, r & 31, r >> 5, tile);
  } else {
    const int r = id - 10240;
    const float* src = (r >> 11) ? enc : y;
    bf16* dst = (r >> 11) ? encbf : ybf;
    const int i = (r & 2047) * 256 + threadIdx.x;
    float4 v = ((const float4*)src)[i];
    ((uint2*)dst)[i] = make_uint2(pk_bf16(v.x, v.y), pk_bf16(v.z, v.w));
  }
}

// ---------------------------------------------------------------------------
// MFMA GEMM: C[M,N] = A[M,Klen] @ Bt[N,Klen]^T (+ bias[N]), optional ReLU.
// Rows strided by Kstride (split-K via pre-offset ptrs).  BK=64: LDS rows are
// 128B / 8 chunks, XOR-swizzled.  Double-buffered 2-phase pipeline: ds_reads
// of tile t first, then stage(t+1) (global_load_lds, no wait), then MFMA;
// one __syncthreads per tile.  Staging sources advance by pointer increment.
// BM in {32,64,128}, BN in {64,128}; 256 thr = 4 waves in 2x2.
// DUALT: also emit C^T bf16 (cvt_pk packed).  grid.z selects problem 0/1.
// ---------------------------------------------------------------------------
template <int BM, int BN, bool RELU, bool DUALT, typename CT>
__global__ __launch_bounds__(256) void mfma_gemm_kernel(
    const bf16* __restrict__ A0, const bf16* __restrict__ Bt0,
    const float* __restrict__ bias0, CT* __restrict__ C0,
    bf16* __restrict__ Ct0,
    const bf16* __restrict__ A1, const bf16* __restrict__ Bt1,
    const float* __restrict__ bias1, CT* __restrict__ C1,
    bf16* __restrict__ Ct1,
    int M, int N, int Kstride, int Klen) {
  const bf16* A = blockIdx.z ? A1 : A0;
  const bf16* Bt = blockIdx.z ? Bt1 : Bt0;
  const float* bias = blockIdx.z ? bias1 : bias0;
  CT* C = blockIdx.z ? C1 : C0;
  bf16* Ct = blockIdx.z ? Ct1 : Ct0;

  constexpr int MF = (BM + 31) / 32;
  constexpr int NF = BN / 32;
  __shared__ __align__(16) bf16 As[2][BM * 64];
  __shared__ __align__(16) bf16 Bs[2][BN * 64];

  const int tid = threadIdx.x;
  const int wave = tid >> 6;
  const int lane = tid & 63;
  const int m0 = blockIdx.y * BM;
  const int n0 = blockIdx.x * BN;
  const int wr = wave >> 1, wc = wave & 1;

  // staging: thread -> row tid>>3 (32 rows / 4096B issue), swizzled chunk
  const int srow = tid >> 3;
  const int schunk = (tid & 7) ^ (srow & 7);
  const bf16* astg = A + (size_t)(m0 + srow) * Kstride + schunk * 8;
  const bf16* bstg = Bt + (size_t)(n0 + srow) * Kstride + schunk * 8;

  floatx4 acc[MF][NF];
#pragma unroll
  for (int i = 0; i < MF; ++i)
#pragma unroll
    for (int j = 0; j < NF; ++j) acc[i][j] = floatx4{0.f, 0.f, 0.f, 0.f};

  const int mrow = lane & 15;
  const int p0 = (((lane >> 4) ^ (mrow & 7)) << 4);  // swizzled chunk pos
  const int p1 = p0 ^ 64;                            // k-step 1 (chunk+4)

  auto stage = [&](int buf) {
    char* al = (char*)As + buf * (BM * 128) + wave * 1024;
    char* bl = (char*)Bs + buf * (BN * 128) + wave * 1024;
#pragma unroll
    for (int i = 0; i < BM / 32; ++i)
      async_ld16(astg + (size_t)(32 * i) * Kstride, al + i * 4096);
#pragma unroll
    for (int i = 0; i < BN / 32; ++i)
      async_ld16(bstg + (size_t)(32 * i) * Kstride, bl + i * 4096);
  };

  stage(0);
  astg += 64;
  bstg += 64;
  __syncthreads();  // drains vmcnt(0): buffer 0 ready

  int cur = 0;
  for (int kt = 0; kt < Klen; kt += 64) {
    const char* abase = (const char*)As + cur * (BM * 128);
    const char* bbase = (const char*)Bs + cur * (BN * 128);
    bf16x8 af0[MF], af1[MF], bf0[NF], bf1[NF];
#pragma unroll
    for (int fi = 0; fi < MF; ++fi) {
      const char* ar = abase + (wr * (BM / 2) + fi * 16 + mrow) * 128;
      af0[fi] = *(const bf16x8*)(ar + p0);
      af1[fi] = *(const bf16x8*)(ar + p1);
    }
#pragma unroll
    for (int fj = 0; fj < NF; ++fj) {
      const char* br = bbase + (wc * (BN / 2) + fj * 16 + mrow) * 128;
      bf0[fj] = *(const bf16x8*)(br + p0);
      bf1[fj] = *(const bf16x8*)(br + p1);
    }

    if (kt + 64 < Klen) {  // prefetch, no wait
      stage(cur ^ 1);
      astg += 64;
      bstg += 64;
    }

#pragma unroll
    for (int fi = 0; fi < MF; ++fi)
#pragma unroll
      for (int fj = 0; fj < NF; ++fj) {
        acc[fi][fj] = __builtin_amdgcn_mfma_f32_16x16x32_bf16(
            af0[fi], bf0[fj], acc[fi][fj], 0, 0, 0);
        acc[fi][fj] = __builtin_amdgcn_mfma_f32_16x16x32_bf16(
            af1[fi], bf1[fj], acc[fi][fj], 0, 0, 0);
      }

    __syncthreads();  // next-tile loads landed; all reads of cur done
    cur ^= 1;
  }

  const int erow = (lane >> 4) * 4;
  const int ecol = lane & 15;
#pragma unroll
  for (int fi = 0; fi < MF; ++fi) {
#pragma unroll
    for (int fj = 0; fj < NF; ++fj) {
      const int nn = n0 + wc * (BN / 2) + fj * 16 + ecol;
      const float bv = bias ? bias[nn] : 0.0f;
      const int mmb = m0 + wr * (BM / 2) + fi * 16 + erow;
      float v[4];
#pragma unroll
      for (int r = 0; r < 4; ++r) {
        v[r] = acc[fi][fj][r] + bv;
        if (RELU) v[r] = fmaxf(v[r], 0.0f);
        if constexpr (sizeof(CT) == 2)
          C[(size_t)(mmb + r) * N + nn] = (CT)__float2bfloat16(v[r]);
        else
          C[(size_t)(mmb + r) * N + nn] = (CT)v[r];
      }
      if (DUALT) {
        *(uint2*)&Ct[(size_t)nn * M + mmb] =
            make_uint2(pk_bf16(v[0], v[1]), pk_bf16(v[2], v[3]));
      }
    }
  }
}

// ---------------------------------------------------------------------------
// MFMA flash attention, fixed-max softmax, split-K partials (k == v).
// Block = 256 thr = 4 waves; wave owns 16 q of a 64-q tile.  KV tile = 64 t
// (R21: halves barrier/loop count vs 32).  K/V double-buffered; per-phase:
// V-frag ds_reads -> prefetch issue (4 DMA) -> per-jt {K-frag reads, QK MFMA,
// exp (v_exp_f32), cvt_pk pack, P store} -> P reads -> PV MFMA -> barrier.
// LDS: Kt 2x8KB [t][d] + Vs 2x8KB [d][t] + Ps 4x2KB [q][t] = 40KB, all 128B
// rows with chunk ^= (row&7) swizzle (K/V pre-applied on global fetch addr).
// P write chunk (2jt+(g>>1))^(c&7) + (g&1)*8 == read chunk (4ks+g)^(c&7)
// under the same row key (bijective, write->read same-wave in-order).
// CAUSAL (template): pair-scheduling -- block processes q-tiles {qb0,31-qb0}
// sequentially (uniform ~17 iters), grid (16,16,2); masks compiled out of
// cross instantiation (grid (32,16,2)).  Element masks also zero the
// fully-masked diagonal fragments (t0+16jt beyond the wave's rows).
// S^T = K.Q^T (C: 4 consecutive t per lane at fixed q); l-reduce 2 shuffles.
// PV: O^T = V^T @ P^T, k=64 as 2 MFMA per d-block.
// Emits UNNORMALIZED O-partial + l-partial; LN merges.
// ---------------------------------------------------------------------------
template <bool CAUSAL>
__global__ __launch_bounds__(256) void mfma_attn_kernel(
    const bf16* __restrict__ Q, const bf16* __restrict__ K,
    const bf16* __restrict__ Vt,
    float* __restrict__ OA, float* __restrict__ OB,
    float* __restrict__ LA, float* __restrict__ LB) {
  __shared__ __align__(16) unsigned short Kt[2][64 * 64];  // [t][d] swizzled
  __shared__ __align__(16) unsigned short Vs[2][64 * 64];  // [d][t] swizzled
  __shared__ __align__(16) unsigned short Ps[4][1024];     // per-wave P [q][t]

  const int tid = threadIdx.x;
  const int w = tid >> 6, lane = tid & 63;
  const int g = lane >> 4, c = lane & 15;
  const int h = blockIdx.y;
  const int z = blockIdx.z;
  float* Oz = z ? OB : OA;
  float* Lz = z ? LB : LA;

  // staging addresses (global pre-swizzled, LDS dest lane-linear).
  // Each 8KB tile = 2 issues: rows r..r+31 then rows r+32..r+63 (row&7 key
  // identical, so the same swizzled chunk works for both).
  const int srow = tid >> 3;                       // 0..31
  const int schk = (tid & 7) ^ (srow & 7);
  const bf16* kgp = K + (size_t)srow * DMODEL + h * DHEAD + schk * 8;
  const bf16* vgp = Vt + (size_t)(h * DHEAD + srow) * S_LEN + schk * 8;

  char* pswave = (char*)Ps + w * 2048;

  // ---- lane-invariant LDS byte offsets (hoisted; pass-invariant too) ----
  int ko[4][2], vo[4][2];
#pragma unroll
  for (int i = 0; i < 4; ++i) {
    ko[i][0] = (16 * i + c) * 128 + (((g) ^ (c & 7)) << 4);
    ko[i][1] = (16 * i + c) * 128 + (((4 + g) ^ (c & 7)) << 4);
    vo[i][0] = ko[i][0];  // V rows d=16*md+c: same formula
    vo[i][1] = ko[i][1];
  }
  char* pw[4];
#pragma unroll
  for (int jt = 0; jt < 4; ++jt)
    pw[jt] = pswave + c * 128 +
             ((((2 * jt + (g >> 1)) ^ (c & 7)) << 4) | ((g & 1) << 3));
  const char* const pr0 = pswave + c * 128 + (((g) ^ (c & 7)) << 4);
  const char* const pr1 = pswave + c * 128 + (((4 + g) ^ (c & 7)) << 4);

  const int npass = CAUSAL ? 2 : 1;
  for (int pass = 0; pass < npass; ++pass) {
    // causal pairing: pass 0 -> qb0 (short), pass 1 -> 31-qb0 (long)
    const int qb = CAUSAL ? (pass ? (S_LEN / 64 - 1) - (int)blockIdx.x
                                  : (int)blockIdx.x)
                          : (int)blockIdx.x;
    const int q0 = qb * 64;
    const int qw = q0 + w * 16;  // this wave's 16-q subtile

    // Q B-frags for the wave's 16-q subtile (d halves 0..31 / 32..63)
    const bf16* qrow = Q + (size_t)(qw + c) * DMODEL + h * DHEAD + g * 8;
    const bf16x8 qfa = *(const bf16x8*)qrow;
    const bf16x8 qfb = *(const bf16x8*)(qrow + 32);

    floatx4 of[4];
#pragma unroll
    for (int i = 0; i < 4; ++i) of[i] = floatx4{0.f, 0.f, 0.f, 0.f};
    float lp0 = 0.f, lp1 = 0.f;

    const int nkt = CAUSAL ? (qb + 1) : (S_LEN / 64);  // 64-t tiles

    // running stage source pointers
    const bf16* kst = kgp + (size_t)(z * 64) * DMODEL;
    const bf16* vst = vgp + z * 64;

    auto stage = [&](int buf) {  // 4 DMA, then advance by 2 tiles (z-parity)
      char* kl = (char*)Kt + buf * 8192 + w * 1024;
      char* vl = (char*)Vs + buf * 8192 + w * 1024;
      async_ld16(kst, kl);
      async_ld16(kst + (size_t)32 * DMODEL, kl + 4096);
      async_ld16(vst, vl);
      async_ld16(vst + (size_t)32 * S_LEN, vl + 4096);
      kst += (size_t)128 * DMODEL;
      vst += 128;
    };

    auto phase = [&](const char* kb, const char* vb, int sbuf, int kt) {
      const int t0 = kt * 64;
      bool act = true;
      if constexpr (CAUSAL) act = (t0 < qw + 16);  // wave-uniform
      bf16x8 vf[4][2];
      if (act) {
#pragma unroll
        for (int md = 0; md < 4; ++md) {
          vf[md][0] = *(const bf16x8*)(vb + vo[md][0]);
          vf[md][1] = *(const bf16x8*)(vb + vo[md][1]);
        }
      }
      if (kt + 2 < nkt) stage(sbuf);  // prefetch next, no wait
      if (act) {
        const bool diag = CAUSAL && (t0 + 64 > qw);
        const int qq = qw + c;
#pragma unroll
        for (int jt = 0; jt < 4; ++jt) {
          const bf16x8 kf0 = *(const bf16x8*)(kb + ko[jt][0]);
          const bf16x8 kf1 = *(const bf16x8*)(kb + ko[jt][1]);
          floatx4 s = floatx4{0.f, 0.f, 0.f, 0.f};
          __builtin_amdgcn_s_setprio(1);
          s = __builtin_amdgcn_mfma_f32_16x16x32_bf16(kf0, qfa, s, 0, 0, 0);
          s = __builtin_amdgcn_mfma_f32_16x16x32_bf16(kf1, qfb, s, 0, 0, 0);
          __builtin_amdgcn_s_setprio(0);

          // p = exp(0.125*s) = 2^(s * 0.125*log2e)
          const float CC = 0.18033688011f;
          float e0, e1, e2, e3;
          {
            float x0 = s[0] * CC, x1 = s[1] * CC;
            float x2 = s[2] * CC, x3 = s[3] * CC;
            asm("v_exp_f32 %0, %1" : "=v"(e0) : "v"(x0));
            asm("v_exp_f32 %0, %1" : "=v"(e1) : "v"(x1));
            asm("v_exp_f32 %0, %1" : "=v"(e2) : "v"(x2));
            asm("v_exp_f32 %0, %1" : "=v"(e3) : "v"(x3));
          }
          if constexpr (CAUSAL) {
            if (diag) {
              const int tb = t0 + 16 * jt + 4 * g;
              if (tb + 0 > qq) e0 = 0.f;
              if (tb + 1 > qq) e1 = 0.f;
              if (tb + 2 > qq) e2 = 0.f;
              if (tb + 3 > qq) e3 = 0.f;
            }
          }
          lp0 += e0 + e1;
          lp1 += e2 + e3;
          *(uint2*)pw[jt] = make_uint2(pk_bf16(e0, e1), pk_bf16(e2, e3));
        }

        // --- O^T += V^T @ P^T (k = 64 as 2 MFMA per d-block) ---
        const bf16x8 pf0 = *(const bf16x8*)pr0;
        const bf16x8 pf1 = *(const bf16x8*)pr1;
        __builtin_amdgcn_s_setprio(1);
#pragma unroll
        for (int md = 0; md < 4; ++md) {
          of[md] = __builtin_amdgcn_mfma_f32_16x16x32_bf16(
              vf[md][0], pf0, of[md], 0, 0, 0);
          of[md] = __builtin_amdgcn_mfma_f32_16x16x32_bf16(
              vf[md][1], pf1, of[md], 0, 0, 0);
        }
        __builtin_amdgcn_s_setprio(0);
      }
      __syncthreads();  // next-tile loads landed; all reads of this buf done
    };

    stage(0);
    __syncthreads();  // buffer 0 ready (drains vmcnt)

    int kt = z;
    while (true) {
      phase((const char*)Kt, (const char*)Vs, 1, kt);  // compute buf0
      kt += 2;
      if (kt >= nkt) break;
      phase((const char*)Kt + 8192, (const char*)Vs + 8192, 0, kt);
      kt += 2;
      if (kt >= nkt) break;
    }

    // --- l reduce (over g-groups) + unnormalized O-partial write ---
    float lpart = lp0 + lp1;
    lpart += __shfl_xor(lpart, 16, 64);
    lpart += __shfl_xor(lpart, 32, 64);
    if (g == 0) Lz[(size_t)h * S_LEN + qw + c] = lpart;
    float* orow = Oz + (size_t)(qw + c) * DMODEL + h * DHEAD;
#pragma unroll
    for (int md = 0; md < 4; ++md) {
      float4 v;
      v.x = of[md][0]; v.y = of[md][1]; v.z = of[md][2]; v.w = of[md][3];
      *(float4*)(orow + md * 16 + 4 * g) = v;
    }
    // next pass: prologue stage + barrier re-fills LDS; epilogue touched no
    // LDS, and the last phase's __syncthreads() ordered all reads before it.
  }
}

// ---------------------------------------------------------------------------
// LayerNorm variants.  One block (256 thr) per row, D=1024; float4 per thread.
// MERGE: x = X + (R+R2) / (La[h][row]+Lb[h][row])   (attention partial merge)
// SUM2 : x = X + R + R2 + bvec                      (split-K FFN + bias)
// else : x = X + R
// ---------------------------------------------------------------------------
template <bool DUAL, bool MERGE, bool SUM2>
__global__ __launch_bounds__(256) void add_ln_kernel(
    const float* __restrict__ X, const float* __restrict__ R,
    const float* __restrict__ R2, const float* __restrict__ bvec,
    const float* __restrict__ La, const float* __restrict__ Lb,
    const float* __restrict__ g, const float* __restrict__ beta,
    float* __restrict__ out, bf16* __restrict__ out2) {
  const int row = blockIdx.x;
  const int tid = threadIdx.x;
  const int c = tid * 4;
  const size_t base = (size_t)row * DMODEL + c;

  float4 x = *(const float4*)&X[base];
  if (MERGE) {
    const int h = c >> 6;
    const float rl =
        1.0f / (La[(size_t)h * S_LEN + row] + Lb[(size_t)h * S_LEN + row]);
    const float4 r = *(const float4*)&R[base];
    const float4 r2 = *(const float4*)&R2[base];
    x.x += (r.x + r2.x) * rl;
    x.y += (r.y + r2.y) * rl;
    x.z += (r.z + r2.z) * rl;
    x.w += (r.w + r2.w) * rl;
  } else if (SUM2) {
    const float4 r = *(const float4*)&R[base];
    const float4 r2 = *(const float4*)&R2[base];
    const float4 bv = *(const float4*)&bvec[c];
    x.x += r.x + r2.x + bv.x;
    x.y += r.y + r2.y + bv.y;
    x.z += r.z + r2.z + bv.z;
    x.w += r.w + r2.w + bv.w;
  } else {
    const float4 r = *(const float4*)&R[base];
    x.x += r.x; x.y += r.y; x.z += r.z; x.w += r.w;
  }
  float s1 = x.x + x.y + x.z + x.w;
  float s2 = x.x * x.x + x.y * x.y + x.z * x.z + x.w * x.w;

#pragma unroll
  for (int off = 32; off; off >>= 1) {
    s1 += __shfl_xor(s1, off, 64);
    s2 += __shfl_xor(s2, off, 64);
  }
  __shared__ float w1s[4], w2s[4];
  const int wid = tid >> 6, lane = tid & 63;
  if (lane == 0) { w1s[wid] = s1; w2s[wid] = s2; }
  __syncthreads();
  s1 = w1s[0] + w1s[1] + w1s[2] + w1s[3];
  s2 = w2s[0] + w2s[1] + w2s[2] + w2s[3];

  const float mu = s1 * (1.0f / DMODEL);
  const float var = s2 * (1.0f / DMODEL) - mu * mu;
  const float rstd = rsqrtf(var + 1e-5f);

  const float4 gg = *(const float4*)&g[c];
  const float4 bb = *(const float4*)&beta[c];
  float4 r;
  r.x = (x.x - mu) * rstd * gg.x + bb.x;
  r.y = (x.y - mu) * rstd * gg.y + bb.y;
  r.z = (x.z - mu) * rstd * gg.z + bb.z;
  r.w = (x.w - mu) * rstd * gg.w + bb.w;
  *(float4*)&out[base] = r;
  if (DUAL) {
    *(uint2*)&out2[base] = make_uint2(pk_bf16(r.x, r.y), pk_bf16(r.z, r.w));
  }
}

// ---------------------------------------------------------------------------
extern "C" void kernel_launch(void* const* d_in, const int* in_sizes, int n_in,
                              void* d_out, int out_size, void* d_ws, size_t ws_size,
                              hipStream_t stream) {
  const float* y      = (const float*)d_in[0];
  const float* enc    = (const float*)d_in[1];
  const float* Wself  = (const float*)d_in[2];
  const float* bself  = (const float*)d_in[3];
  const float* Wcross = (const float*)d_in[4];
  const float* bcross = (const float*)d_in[5];
  const float* g1     = (const float*)d_in[6];
  const float* be1    = (const float*)d_in[7];
  const float* g2     = (const float*)d_in[8];
  const float* be2    = (const float*)d_in[9];
  const float* g3     = (const float*)d_in[10];
  const float* be3    = (const float*)d_in[11];
  const float* w1     = (const float*)d_in[12];
  const float* b1     = (const float*)d_in[13];
  const float* w2     = (const float*)d_in[14];
  const float* b2     = (const float*)d_in[15];
  float* out = (float*)d_out;

  char* ws = (char*)d_ws;
  const size_t MB = 1024 * 1024;
  bf16*  ybf   = (bf16*)(ws + 0 * MB);
  bf16*  encbf = (bf16*)(ws + 4 * MB);
  float* PA    = (float*)(ws + 0 * MB);
  float* PB    = (float*)(ws + 8 * MB);
  float* Y1    = (float*)(ws + 16 * MB);
  float* Y2    = (float*)(ws + 24 * MB);
  bf16*  Q12b  = (bf16*)(ws + 32 * MB);
  bf16*  Q1t   = (bf16*)(ws + 36 * MB);
  bf16*  K2b   = (bf16*)(ws + 40 * MB);
  bf16*  K2t   = (bf16*)(ws + 44 * MB);
  bf16*  w1t   = (bf16*)(ws + 48 * MB);
  bf16*  w2t   = (bf16*)(ws + 56 * MB);
  bf16*  Wst   = (bf16*)(ws + 64 * MB);
  bf16*  Wct   = (bf16*)(ws + 66 * MB);
  bf16*  Y1bf  = (bf16*)(ws + 68 * MB);
  bf16*  Y2bf  = (bf16*)(ws + 72 * MB);
  float* La    = (float*)(ws + 76 * MB);
  float* Lb    = (float*)(ws + 76 * MB + 512 * 1024);
  bf16*  FFH   = (bf16*)(ws + 0 * MB);    // 16 MB, overlays dead PA+PB
  float* FFa   = (float*)(ws + 32 * MB);  // overlays dead Q12b+Q1t
  float* FFb   = (float*)(ws + 40 * MB);  // overlays dead K2b+K2t

  const dim3 blk(256);
  const dim3 gFused(14336);                         // 3 transp + conv fused
  const dim3 gProj2(DMODEL / 64, S_LEN / 128, 2);   // 512 blocks (128x64)
  const dim3 gProj(DMODEL / 64, S_LEN / 64);        // 512 (64x64)
  const dim3 gFf1(HIDDEN / 128, S_LEN / 128);       // 512 (128x128)
  const dim3 gFf2(DMODEL / 64, S_LEN / 128, 2);     // 512 (128x64 split-K)
  const dim3 gAttnC(S_LEN / 128, NHEAD, 2);         // 512 (paired causal)
  const dim3 gAttnX(S_LEN / 64, NHEAD, 2);          // 1024 (cross)
  const dim3 gLn(S_LEN);

  // --- conversions (one launch) ---
  fused_conv_kernel<<<gFused, blk, 0, stream>>>(
      Wself, Wst, Wcross, Wct, w1, w1t, w2, w2t, y, ybf, enc, encbf);

  // 1+4) Q1 = y@Wself+bself ; K2 = enc@Wcross+bcross  (dual C+C^T, one launch)
  mfma_gemm_kernel<128, 64, false, true, bf16><<<gProj2, blk, 0, stream>>>(
      ybf, Wst, bself, Q12b, Q1t,
      encbf, Wct, bcross, K2b, K2t, S_LEN, DMODEL, DMODEL, DMODEL);
  // 2) self-attention (causal, paired q-tiles), k=v=Q1; unnormalized partials
  mfma_attn_kernel<true><<<gAttnC, blk, 0, stream>>>(
      Q12b, Q12b, Q1t, PA, PB, La, Lb);
  // 3) y1 = LN(y + (PA+PB)/(La+Lb))  (+ bf16 copy)
  add_ln_kernel<true, true, false><<<gLn, blk, 0, stream>>>(
      y, PA, PB, nullptr, La, Lb, g1, be1, Y1, Y1bf);
  // 5) Q2 = y1 @ Wcross + bcross  (64x64: 512 blocks)
  mfma_gemm_kernel<64, 64, false, false, bf16><<<gProj, blk, 0, stream>>>(
      Y1bf, Wct, bcross, Q12b, nullptr,
      nullptr, nullptr, nullptr, nullptr, nullptr, S_LEN, DMODEL, DMODEL, DMODEL);
  // 6) cross-attention (full), k=v=K2
  mfma_attn_kernel<false><<<gAttnX, blk, 0, stream>>>(
      Q12b, K2b, K2t, PA, PB, La, Lb);
  // 7) y2 = LN(y1 + (PA+PB)/(La+Lb))  (+ bf16 copy)
  add_ln_kernel<true, true, false><<<gLn, blk, 0, stream>>>(
      Y1, PA, PB, nullptr, La, Lb, g2, be2, Y2, Y2bf);
  // 8) ffh = relu(y2 @ w1 + b1) -> bf16  (128x128: 512 blocks)
  mfma_gemm_kernel<128, 128, true, false, bf16><<<gFf1, blk, 0, stream>>>(
      Y2bf, w1t, b1, FFH, nullptr,
      nullptr, nullptr, nullptr, nullptr, nullptr, S_LEN, HIDDEN, DMODEL, DMODEL);
  // 9) split-K FFN2 (128x64: 512 blocks, K=2048 each)
  mfma_gemm_kernel<128, 64, false, false, float><<<gFf2, blk, 0, stream>>>(
      FFH, w2t, nullptr, FFa, nullptr,
      FFH + HIDDEN / 2, w2t + HIDDEN / 2, nullptr, FFb, nullptr,
      S_LEN, DMODEL, HIDDEN, HIDDEN / 2);
  // 10) out = LN(y2 + FFa + FFb + b2)
  add_ln_kernel<false, false, true><<<gLn, blk, 0, stream>>>(
      Y2, FFa, FFb, b2, nullptr, nullptr, g3, be3, out, nullptr);
}